// Round 1
// baseline (613.168 us; speedup 1.0000x reference)
//
#include <hip/hip_runtime.h>
#include <math.h>

namespace {
constexpr int N = 1000000;
constexpr int E = 1000000;
constexpr int C = 64;            // poss_node cols; poss_edge rows have C+1 = 65 floats
constexpr int BLOCK = 256;
constexpr int GROUPS_PER_BLOCK = BLOCK / 16;     // 16-lane group per edge/row

// ---- fast path (f16 re-layout) config ----
constexpr int PREP_BLOCKS = 2048;
constexpr int EDGE_BLOCKS = 2048;
constexpr int PREP_GROUPS = PREP_BLOCKS * GROUPS_PER_BLOCK;   // 32768
constexpr int EDGE_GROUPS = EDGE_BLOCKS * GROUPS_PER_BLOCK;   // 32768

// ---- fallback path (original, R1-proven) config ----
constexpr int NODE_BLOCKS_F = 1024;
constexpr int EDGE_BLOCKS_F = 2048;
constexpr int TOTAL_GROUPS_F = EDGE_BLOCKS_F * GROUPS_PER_BLOCK;

constexpr double SEMI_LAMBDA = 0.5;
constexpr double EDGE_LAMBDA = 1.0;

constexpr size_t PE16_ELEMS = (size_t)E * C;                  // ushort elements
constexpr size_t WS_NEEDED  = PE16_ELEMS * 2                  // f16 copy (128 MB)
                            + (size_t)E * 4                   // plast   (4 MB)
                            + (size_t)3 * PREP_BLOCKS * 4     // prep partials
                            + (size_t)3 * EDGE_BLOCKS * 4;    // edge partials
}

union H4 { uint2 u2; _Float16 h[4]; };

__device__ __forceinline__ float waveReduceSum(float v) {
#pragma unroll
    for (int off = 32; off > 0; off >>= 1) v += __shfl_down(v, off, 64);
    return v;
}

// ================================ FAST PATH ====================================

// node-loss phase: -sum(mask * log p[i, gt[i]]) partials (fused into prep)
__device__ __forceinline__ void node_phase(const float* __restrict__ poss_node,
                                           const int* __restrict__ gt,
                                           const int* __restrict__ mask,
                                           float& lsum, float& cnt) {
    for (int i = blockIdx.x * BLOCK + threadIdx.x; i < N; i += PREP_BLOCKS * BLOCK) {
        if (mask[i] != 0) {
            lsum += logf(poss_node[(size_t)i * C + gt[i]]);
            cnt += 1.f;
        }
    }
}

// row phase: stream poss_edge once; emit f16 copy of cols 0..63 (128B-aligned rows),
// plast[] (fp32 col 64), and s1 = sum(1 - p_last) exactly.
__device__ __forceinline__ void row_phase(const float* __restrict__ poss_edge,
                                          unsigned short* __restrict__ pe16,
                                          float* __restrict__ plast,
                                          float& s1) {
    const int t = threadIdx.x & 15;
    const int g = blockIdx.x * GROUPS_PER_BLOCK + (threadIdx.x >> 4);
    for (int r = g; r < E; r += PREP_GROUPS) {
        const float* __restrict__ row = poss_edge + (size_t)r * (C + 1);
        H4 h;
        h.h[0] = (_Float16)row[4 * t + 0];
        h.h[1] = (_Float16)row[4 * t + 1];
        h.h[2] = (_Float16)row[4 * t + 2];
        h.h[3] = (_Float16)row[4 * t + 3];
        *reinterpret_cast<uint2*>(pe16 + (size_t)r * C + 4 * t) = h.u2;  // 16 lanes -> 128B row
        if (t == 0) {
            const float pl = row[C];
            plast[r] = pl;
            s1 += 1.f - pl;
        }
    }
}

__global__ __launch_bounds__(BLOCK) void prep_kernel(
    const float* __restrict__ poss_node,
    const float* __restrict__ poss_edge,
    const int* __restrict__ gt,
    const int* __restrict__ mask,
    unsigned short* __restrict__ pe16,
    float* __restrict__ plast,
    float* __restrict__ partials)   // [3][PREP_BLOCKS]: lsum, cnt, s1
{
    float lsum = 0.f, cnt = 0.f, s1 = 0.f;
    // half the blocks gather (node) while the other half streams (rows): BW overlap
    if (blockIdx.x & 1) {
        node_phase(poss_node, gt, mask, lsum, cnt);
        row_phase(poss_edge, pe16, plast, s1);
    } else {
        row_phase(poss_edge, pe16, plast, s1);
        node_phase(poss_node, gt, mask, lsum, cnt);
    }

    __shared__ float s[3][BLOCK / 64];
    lsum = waveReduceSum(lsum);
    cnt  = waveReduceSum(cnt);
    s1   = waveReduceSum(s1);
    const int lane = threadIdx.x & 63, wv = threadIdx.x >> 6;
    if (lane == 0) { s[0][wv] = lsum; s[1][wv] = cnt; s[2][wv] = s1; }
    __syncthreads();
    if (threadIdx.x == 0) {
        float a = 0.f, b = 0.f, c = 0.f;
#pragma unroll
        for (int w = 0; w < BLOCK / 64; ++w) { a += s[0][w]; b += s[1][w]; c += s[2][w]; }
        partials[0 * PREP_BLOCKS + blockIdx.x] = a;
        partials[1 * PREP_BLOCKS + blockIdx.x] = b;
        partials[2 * PREP_BLOCKS + blockIdx.x] = c;
    }
}

// gather kernel: 16-lane group per edge; 128B aligned f16 row pairs (L3-resident)
__global__ __launch_bounds__(BLOCK) void edge16_kernel(
    const unsigned short* __restrict__ pe16,
    const float* __restrict__ plast,
    const int* __restrict__ gt,
    const int* __restrict__ mask,
    const int* __restrict__ edges,
    float* __restrict__ partials)   // [3][EDGE_BLOCKS]: sq, pos, lcnt
{
    const int t = threadIdx.x & 15;
    const int g = blockIdx.x * GROUPS_PER_BLOCK + (threadIdx.x >> 4);

    float sq = 0.f, pos = 0.f, lcnt = 0.f;

    for (int e = g; e < E; e += EDGE_GROUPS) {
        const int2 ep = *(const int2*)(edges + 2 * (size_t)e);
        const int e0 = ep.x, e1 = ep.y;

        H4 ha, hb;
        ha.u2 = *reinterpret_cast<const uint2*>(pe16 + (size_t)e0 * C + 4 * t);
        hb.u2 = *reinterpret_cast<const uint2*>(pe16 + (size_t)e1 * C + 4 * t);
        const float d0 = (float)ha.h[0] - (float)hb.h[0];
        const float d1 = (float)ha.h[1] - (float)hb.h[1];
        const float d2 = (float)ha.h[2] - (float)hb.h[2];
        const float d3 = (float)ha.h[3] - (float)hb.h[3];
        float acc = fmaf(d0, d0, fmaf(d1, d1, fmaf(d2, d2, d3 * d3)));
        if (t == 0) {   // col 64 in exact fp32 from plast[]
            const float dl = plast[e0] - plast[e1];
            acc = fmaf(dl, dl, acc);
        }
        sq += acc;

        // per-edge scalar terms (group-uniform; broadcast loads; L2-resident arrays)
        const float p_last = plast[e];
        const int m0 = (mask[e0] != 0);
        const int m1 = (mask[e1] != 0);
        if (m0 | m1) {
            const int g0 = gt[e0];
            const int g1 = gt[e1];
            float contrib;
            if (m0 & m1) {
                contrib = (g0 == g1)
                    ? logf((float)*reinterpret_cast<const _Float16*>(pe16 + (size_t)e * C + g0))
                    : logf(p_last);
            } else if (m0) {
                contrib = logf(p_last + (float)*reinterpret_cast<const _Float16*>(pe16 + (size_t)e * C + g0));
            } else {
                contrib = logf(p_last + (float)*reinterpret_cast<const _Float16*>(pe16 + (size_t)e * C + g1));
            }
            if (t == 0) { pos += contrib; lcnt += 1.f; }
        }
    }

    __shared__ float s[3][BLOCK / 64];
    sq   = waveReduceSum(sq);
    pos  = waveReduceSum(pos);
    lcnt = waveReduceSum(lcnt);
    const int lane = threadIdx.x & 63, wv = threadIdx.x >> 6;
    if (lane == 0) { s[0][wv] = sq; s[1][wv] = pos; s[2][wv] = lcnt; }
    __syncthreads();
    if (threadIdx.x == 0) {
        float a = 0.f, b = 0.f, c = 0.f;
#pragma unroll
        for (int w = 0; w < BLOCK / 64; ++w) { a += s[0][w]; b += s[1][w]; c += s[2][w]; }
        partials[0 * EDGE_BLOCKS + blockIdx.x] = a;
        partials[1 * EDGE_BLOCKS + blockIdx.x] = b;
        partials[2 * EDGE_BLOCKS + blockIdx.x] = c;
    }
}

__global__ __launch_bounds__(BLOCK) void finalize16_kernel(
    const float* __restrict__ prep_partials,   // [3][PREP_BLOCKS]
    const float* __restrict__ edge_partials,   // [3][EDGE_BLOCKS]
    float* __restrict__ out)
{
    double a0 = 0, a1 = 0, a2 = 0, a3 = 0, a4 = 0, a5 = 0;
    for (int i = threadIdx.x; i < PREP_BLOCKS; i += BLOCK) {
        a0 += (double)prep_partials[0 * PREP_BLOCKS + i];
        a1 += (double)prep_partials[1 * PREP_BLOCKS + i];
        a2 += (double)prep_partials[2 * PREP_BLOCKS + i];
    }
    for (int i = threadIdx.x; i < EDGE_BLOCKS; i += BLOCK) {
        a3 += (double)edge_partials[0 * EDGE_BLOCKS + i];
        a4 += (double)edge_partials[1 * EDGE_BLOCKS + i];
        a5 += (double)edge_partials[2 * EDGE_BLOCKS + i];
    }
#pragma unroll
    for (int off = 32; off > 0; off >>= 1) {
        a0 += __shfl_down(a0, off, 64);
        a1 += __shfl_down(a1, off, 64);
        a2 += __shfl_down(a2, off, 64);
        a3 += __shfl_down(a3, off, 64);
        a4 += __shfl_down(a4, off, 64);
        a5 += __shfl_down(a5, off, 64);
    }
    __shared__ double sd[6][BLOCK / 64];
    const int lane = threadIdx.x & 63, wv = threadIdx.x >> 6;
    if (lane == 0) {
        sd[0][wv] = a0; sd[1][wv] = a1; sd[2][wv] = a2;
        sd[3][wv] = a3; sd[4][wv] = a4; sd[5][wv] = a5;
    }
    __syncthreads();
    if (threadIdx.x == 0) {
        double t[6];
#pragma unroll
        for (int k = 0; k < 6; ++k) {
            double v = 0;
#pragma unroll
            for (int w = 0; w < BLOCK / 64; ++w) v += sd[k][w];
            t[k] = v;
        }
        const double loss      = -t[0] / t[1];
        const double semi      = SEMI_LAMBDA * t[2] * t[3];
        const double edge_loss = (-t[4]) * (EDGE_LAMBDA * EDGE_LAMBDA) / (t[5] * t[5]);
        out[0] = (float)(loss + semi + edge_loss);
    }
}

// ============================== FALLBACK PATH ==================================
// Original R1-proven kernels, used only if ws_size < WS_NEEDED.

__global__ __launch_bounds__(BLOCK) void node_kernel_f(
    const float* __restrict__ poss_node,
    const int* __restrict__ gt,
    const int* __restrict__ mask,
    float* __restrict__ partials)   // [2][NODE_BLOCKS_F]
{
    float lsum = 0.f, cnt = 0.f;
    for (int i = blockIdx.x * BLOCK + threadIdx.x; i < N; i += NODE_BLOCKS_F * BLOCK) {
        if (mask[i] != 0) {
            lsum += logf(poss_node[(size_t)i * C + gt[i]]);
            cnt += 1.f;
        }
    }
    __shared__ float s0[BLOCK / 64], s1[BLOCK / 64];
    lsum = waveReduceSum(lsum);
    cnt  = waveReduceSum(cnt);
    const int lane = threadIdx.x & 63, wv = threadIdx.x >> 6;
    if (lane == 0) { s0[wv] = lsum; s1[wv] = cnt; }
    __syncthreads();
    if (threadIdx.x == 0) {
        float a = 0.f, b = 0.f;
#pragma unroll
        for (int w = 0; w < BLOCK / 64; ++w) { a += s0[w]; b += s1[w]; }
        partials[blockIdx.x]                 = a;
        partials[NODE_BLOCKS_F + blockIdx.x] = b;
    }
}

__global__ __launch_bounds__(BLOCK) void edge_kernel_f(
    const float* __restrict__ poss_edge,
    const int* __restrict__ gt,
    const int* __restrict__ mask,
    const int* __restrict__ edges,
    float* __restrict__ partials)   // [4][EDGE_BLOCKS_F]
{
    const int t   = threadIdx.x & 15;
    const int grp = threadIdx.x >> 4;
    const int globalGroup = blockIdx.x * GROUPS_PER_BLOCK + grp;

    float s1 = 0.f, sq = 0.f, pos = 0.f, lcnt = 0.f;

    for (int e = globalGroup; e < E; e += TOTAL_GROUPS_F) {
        const int2 ep = *(const int2*)(edges + 2 * (size_t)e);
        const int e0 = ep.x, e1 = ep.y;

        const float* __restrict__ ra = poss_edge + (size_t)e0 * (C + 1);
        const float* __restrict__ rb = poss_edge + (size_t)e1 * (C + 1);
        const float* __restrict__ re = poss_edge + (size_t)e  * (C + 1);

        const float a0 = ra[t], a1 = ra[t + 16], a2 = ra[t + 32], a3 = ra[t + 48];
        const float b0 = rb[t], b1 = rb[t + 16], b2 = rb[t + 32], b3 = rb[t + 48];
        const float d0 = a0 - b0, d1 = a1 - b1, d2 = a2 - b2, d3 = a3 - b3;
        float acc = fmaf(d0, d0, fmaf(d1, d1, fmaf(d2, d2, d3 * d3)));
        if (t == 0) {
            const float dl = ra[C] - rb[C];
            acc = fmaf(dl, dl, acc);
        }
        sq += acc;

        const float p_last = re[C];
        const int m0 = (mask[e0] != 0);
        const int m1 = (mask[e1] != 0);
        if (m0 | m1) {
            const int g0 = gt[e0];
            const int g1 = gt[e1];
            float contrib;
            if (m0 & m1) {
                contrib = (g0 == g1) ? logf(re[g0]) : logf(p_last);
            } else if (m0) {
                contrib = logf(p_last + re[g0]);
            } else {
                contrib = logf(p_last + re[g1]);
            }
            if (t == 0) { pos += contrib; lcnt += 1.f; }
        }
        if (t == 0) s1 += 1.f - p_last;
    }

    __shared__ float s[4][BLOCK / 64];
    s1   = waveReduceSum(s1);
    sq   = waveReduceSum(sq);
    pos  = waveReduceSum(pos);
    lcnt = waveReduceSum(lcnt);
    const int lane = threadIdx.x & 63, wv = threadIdx.x >> 6;
    if (lane == 0) { s[0][wv] = s1; s[1][wv] = sq; s[2][wv] = pos; s[3][wv] = lcnt; }
    __syncthreads();
    if (threadIdx.x == 0) {
        float a = 0.f, b = 0.f, c = 0.f, d = 0.f;
#pragma unroll
        for (int w = 0; w < BLOCK / 64; ++w) {
            a += s[0][w]; b += s[1][w]; c += s[2][w]; d += s[3][w];
        }
        partials[0 * EDGE_BLOCKS_F + blockIdx.x] = a;
        partials[1 * EDGE_BLOCKS_F + blockIdx.x] = b;
        partials[2 * EDGE_BLOCKS_F + blockIdx.x] = c;
        partials[3 * EDGE_BLOCKS_F + blockIdx.x] = d;
    }
}

__global__ __launch_bounds__(BLOCK) void finalize_kernel_f(
    const float* __restrict__ node_partials,
    const float* __restrict__ edge_partials,
    float* __restrict__ out)
{
    double a0 = 0, a1 = 0, a2 = 0, a3 = 0, a4 = 0, a5 = 0;
    for (int i = threadIdx.x; i < NODE_BLOCKS_F; i += BLOCK) {
        a0 += (double)node_partials[i];
        a1 += (double)node_partials[NODE_BLOCKS_F + i];
    }
    for (int i = threadIdx.x; i < EDGE_BLOCKS_F; i += BLOCK) {
        a2 += (double)edge_partials[0 * EDGE_BLOCKS_F + i];
        a3 += (double)edge_partials[1 * EDGE_BLOCKS_F + i];
        a4 += (double)edge_partials[2 * EDGE_BLOCKS_F + i];
        a5 += (double)edge_partials[3 * EDGE_BLOCKS_F + i];
    }
#pragma unroll
    for (int off = 32; off > 0; off >>= 1) {
        a0 += __shfl_down(a0, off, 64);
        a1 += __shfl_down(a1, off, 64);
        a2 += __shfl_down(a2, off, 64);
        a3 += __shfl_down(a3, off, 64);
        a4 += __shfl_down(a4, off, 64);
        a5 += __shfl_down(a5, off, 64);
    }
    __shared__ double sd[6][BLOCK / 64];
    const int lane = threadIdx.x & 63, wv = threadIdx.x >> 6;
    if (lane == 0) {
        sd[0][wv] = a0; sd[1][wv] = a1; sd[2][wv] = a2;
        sd[3][wv] = a3; sd[4][wv] = a4; sd[5][wv] = a5;
    }
    __syncthreads();
    if (threadIdx.x == 0) {
        double t[6];
#pragma unroll
        for (int k = 0; k < 6; ++k) {
            double v = 0;
#pragma unroll
            for (int w = 0; w < BLOCK / 64; ++w) v += sd[k][w];
            t[k] = v;
        }
        const double loss      = -t[0] / t[1];
        const double semi      = SEMI_LAMBDA * t[2] * t[3];
        const double edge_loss = (-t[4]) * (EDGE_LAMBDA * EDGE_LAMBDA) / (t[5] * t[5]);
        out[0] = (float)(loss + semi + edge_loss);
    }
}

// ================================= LAUNCH ======================================

extern "C" void kernel_launch(void* const* d_in, const int* in_sizes, int n_in,
                              void* d_out, int out_size, void* d_ws, size_t ws_size,
                              hipStream_t stream) {
    const float* poss_node = (const float*)d_in[0];
    const float* poss_edge = (const float*)d_in[1];
    const int*   gt        = (const int*)d_in[2];
    const int*   mask      = (const int*)d_in[3];
    const int*   edges     = (const int*)d_in[4];
    float*       out       = (float*)d_out;

    if (ws_size >= WS_NEEDED) {
        // fast path: f16 re-layout + L3-resident gather
        unsigned short* pe16          = (unsigned short*)d_ws;
        float*          plast         = (float*)(pe16 + PE16_ELEMS);
        float*          prep_partials = plast + E;                       // 3 * PREP_BLOCKS
        float*          edge_partials = prep_partials + 3 * PREP_BLOCKS; // 3 * EDGE_BLOCKS

        prep_kernel<<<PREP_BLOCKS, BLOCK, 0, stream>>>(
            poss_node, poss_edge, gt, mask, pe16, plast, prep_partials);
        edge16_kernel<<<EDGE_BLOCKS, BLOCK, 0, stream>>>(
            pe16, plast, gt, mask, edges, edge_partials);
        finalize16_kernel<<<1, BLOCK, 0, stream>>>(prep_partials, edge_partials, out);
    } else {
        // fallback: original proven path (ws layout 40960 B)
        float* node_partials = (float*)d_ws;                         // 2 * NODE_BLOCKS_F
        float* edge_partials = node_partials + 2 * NODE_BLOCKS_F;    // 4 * EDGE_BLOCKS_F

        node_kernel_f<<<NODE_BLOCKS_F, BLOCK, 0, stream>>>(poss_node, gt, mask, node_partials);
        edge_kernel_f<<<EDGE_BLOCKS_F, BLOCK, 0, stream>>>(poss_edge, gt, mask, edges, edge_partials);
        finalize_kernel_f<<<1, BLOCK, 0, stream>>>(node_partials, edge_partials, out);
    }
}

// Round 2
// 567.703 us; speedup vs baseline: 1.0801x; 1.0801x over previous
//
#include <hip/hip_runtime.h>
#include <math.h>

namespace {
constexpr int N = 1000000;
constexpr int E = 1000000;
constexpr int C = 64;            // poss_node cols; poss_edge rows have C+1 = 65 floats
constexpr int BLOCK = 256;
constexpr int GROUPS_PER_BLOCK = BLOCK / 16;     // 16-lane group (prep)
constexpr int GROUPS8_PER_BLOCK = BLOCK / 8;     // 8-lane group (sq gather)

// ---- fast path config ----
constexpr int NODE_BLOCKS = 1024;
constexpr int PREP_BLOCKS = 2048;
constexpr int SQ_BLOCKS   = 2048;
constexpr int PREP_GROUPS = PREP_BLOCKS * GROUPS_PER_BLOCK;   // 32768
constexpr int SQ_GROUPS   = SQ_BLOCKS * GROUPS8_PER_BLOCK;    // 65536

// ---- fallback path (original, R1-proven) config ----
constexpr int NODE_BLOCKS_F = 1024;
constexpr int EDGE_BLOCKS_F = 2048;
constexpr int TOTAL_GROUPS_F = EDGE_BLOCKS_F * GROUPS_PER_BLOCK;

constexpr double SEMI_LAMBDA = 0.5;
constexpr double EDGE_LAMBDA = 1.0;

constexpr size_t PE16_ELEMS = (size_t)E * C;                  // ushort elements
constexpr size_t WS_NEEDED  = PE16_ELEMS * 2                  // f16 copy (128 MB)
                            + (size_t)E * 4                   // plast   (4 MB)
                            + (size_t)2 * NODE_BLOCKS * 4
                            + (size_t)3 * PREP_BLOCKS * 4
                            + (size_t)1 * SQ_BLOCKS * 4;
}

union H4 { uint2 u2; _Float16 h[4]; };
union H8 { uint4 u4; _Float16 h[8]; };

__device__ __forceinline__ float waveReduceSum(float v) {
#pragma unroll
    for (int off = 32; off > 0; off >>= 1) v += __shfl_down(v, off, 64);
    return v;
}

// extract column `col` (0..63) of the row held 4-per-lane across a 16-lane group
__device__ __forceinline__ float groupExtract(float c0, float c1, float c2, float c3,
                                              int col, int waveBase) {
    const int slot = col & 3;
    const float lo  = (slot & 1) ? c1 : c0;
    const float hi  = (slot & 1) ? c3 : c2;
    const float sel = (slot & 2) ? hi : lo;
    return __shfl(sel, waveBase + (col >> 2), 64);
}

// ================================ FAST PATH ====================================

// ---------------- node loss: -sum(mask * log p[i, gt[i]]) / sum(mask) ----------
__global__ __launch_bounds__(BLOCK) void node_kernel(
    const float* __restrict__ poss_node,
    const int* __restrict__ gt,
    const int* __restrict__ mask,
    float* __restrict__ partials)   // [2][NODE_BLOCKS]
{
    float lsum = 0.f, cnt = 0.f;
    for (int i = blockIdx.x * BLOCK + threadIdx.x; i < N; i += NODE_BLOCKS * BLOCK) {
        if (mask[i] != 0) {
            lsum += logf(poss_node[(size_t)i * C + gt[i]]);
            cnt += 1.f;
        }
    }
    __shared__ float s0[BLOCK / 64], s1[BLOCK / 64];
    lsum = waveReduceSum(lsum);
    cnt  = waveReduceSum(cnt);
    const int lane = threadIdx.x & 63, wv = threadIdx.x >> 6;
    if (lane == 0) { s0[wv] = lsum; s1[wv] = cnt; }
    __syncthreads();
    if (threadIdx.x == 0) {
        float a = 0.f, b = 0.f;
#pragma unroll
        for (int w = 0; w < BLOCK / 64; ++w) { a += s0[w]; b += s1[w]; }
        partials[blockIdx.x]               = a;
        partials[NODE_BLOCKS + blockIdx.x] = b;
    }
}

// ---- prep: PURE sequential stream over poss_edge.
// Emits f16 copy (128B rows) + plast, computes s1 AND the per-edge scalar loss
// terms (pos, lcnt) using the in-register row values (exact fp32).
__global__ __launch_bounds__(BLOCK) void prep_kernel(
    const float* __restrict__ poss_edge,
    const int* __restrict__ gt,
    const int* __restrict__ mask,
    const int* __restrict__ edges,
    unsigned short* __restrict__ pe16,
    float* __restrict__ plast,
    float* __restrict__ partials)   // [3][PREP_BLOCKS]: s1, pos, lcnt
{
    const int t = threadIdx.x & 15;
    const int g = blockIdx.x * GROUPS_PER_BLOCK + (threadIdx.x >> 4);
    const int waveBase = threadIdx.x & 48;          // group base lane within wave

    float s1 = 0.f, pos = 0.f, lcnt = 0.f;

    for (int r = g; r < E; r += PREP_GROUPS) {
        const float* __restrict__ row = poss_edge + (size_t)r * (C + 1);
        const float c0 = row[4 * t + 0];
        const float c1 = row[4 * t + 1];
        const float c2 = row[4 * t + 2];
        const float c3 = row[4 * t + 3];
        H4 h;
        h.h[0] = (_Float16)c0; h.h[1] = (_Float16)c1;
        h.h[2] = (_Float16)c2; h.h[3] = (_Float16)c3;
        *reinterpret_cast<uint2*>(pe16 + (size_t)r * C + 4 * t) = h.u2;

        const float pl = row[C];                    // broadcast load (group-uniform)
        if (t == 0) {
            plast[r] = pl;
            s1 += 1.f - pl;
        }

        // per-edge scalar terms for edge r (row r IS re) — exact fp32
        const int2 ep = *(const int2*)(edges + 2 * (size_t)r);
        const int m0 = (mask[ep.x] != 0);
        const int m1 = (mask[ep.y] != 0);
        if (m0 | m1) {
            float contrib;
            if (m0 & m1) {
                const int g0 = gt[ep.x];
                const int g1 = gt[ep.y];
                if (g0 == g1) {
                    contrib = logf(groupExtract(c0, c1, c2, c3, g0, waveBase));
                } else {
                    contrib = logf(pl);
                }
            } else {
                const int gg = m0 ? gt[ep.x] : gt[ep.y];
                contrib = logf(pl + groupExtract(c0, c1, c2, c3, gg, waveBase));
            }
            if (t == 0) { pos += contrib; lcnt += 1.f; }
        }
    }

    __shared__ float s[3][BLOCK / 64];
    s1   = waveReduceSum(s1);
    pos  = waveReduceSum(pos);
    lcnt = waveReduceSum(lcnt);
    const int lane = threadIdx.x & 63, wv = threadIdx.x >> 6;
    if (lane == 0) { s[0][wv] = s1; s[1][wv] = pos; s[2][wv] = lcnt; }
    __syncthreads();
    if (threadIdx.x == 0) {
        float a = 0.f, b = 0.f, c = 0.f;
#pragma unroll
        for (int w = 0; w < BLOCK / 64; ++w) { a += s[0][w]; b += s[1][w]; c += s[2][w]; }
        partials[0 * PREP_BLOCKS + blockIdx.x] = a;
        partials[1 * PREP_BLOCKS + blockIdx.x] = b;
        partials[2 * PREP_BLOCKS + blockIdx.x] = c;
    }
}

// ---- sq gather: minimal. 8-lane group per edge; one uint4 (16B) per lane per row.
__global__ __launch_bounds__(BLOCK) void sq_kernel(
    const unsigned short* __restrict__ pe16,
    const float* __restrict__ plast,
    const int* __restrict__ edges,
    float* __restrict__ partials)   // [SQ_BLOCKS]
{
    const int t = threadIdx.x & 7;
    const int g = blockIdx.x * GROUPS8_PER_BLOCK + (threadIdx.x >> 3);

    float sq = 0.f;

    for (int e = g; e < E; e += SQ_GROUPS) {
        const int2 ep = *(const int2*)(edges + 2 * (size_t)e);   // broadcast
        H8 ha, hb;
        ha.u4 = *reinterpret_cast<const uint4*>(pe16 + (size_t)ep.x * C + 8 * t);
        hb.u4 = *reinterpret_cast<const uint4*>(pe16 + (size_t)ep.y * C + 8 * t);
        float acc = 0.f;
#pragma unroll
        for (int k = 0; k < 8; ++k) {
            const float d = (float)ha.h[k] - (float)hb.h[k];
            acc = fmaf(d, d, acc);
        }
        if (t == 0) {   // col 64 exact fp32
            const float dl = plast[ep.x] - plast[ep.y];
            acc = fmaf(dl, dl, acc);
        }
        sq += acc;
    }

    __shared__ float s[BLOCK / 64];
    sq = waveReduceSum(sq);
    const int lane = threadIdx.x & 63, wv = threadIdx.x >> 6;
    if (lane == 0) s[wv] = sq;
    __syncthreads();
    if (threadIdx.x == 0) {
        float a = 0.f;
#pragma unroll
        for (int w = 0; w < BLOCK / 64; ++w) a += s[w];
        partials[blockIdx.x] = a;
    }
}

__global__ __launch_bounds__(BLOCK) void finalize16_kernel(
    const float* __restrict__ node_partials,   // [2][NODE_BLOCKS]
    const float* __restrict__ prep_partials,   // [3][PREP_BLOCKS]
    const float* __restrict__ sq_partials,     // [SQ_BLOCKS]
    float* __restrict__ out)
{
    double a0 = 0, a1 = 0, a2 = 0, a3 = 0, a4 = 0, a5 = 0;
    for (int i = threadIdx.x; i < NODE_BLOCKS; i += BLOCK) {
        a0 += (double)node_partials[i];
        a1 += (double)node_partials[NODE_BLOCKS + i];
    }
    for (int i = threadIdx.x; i < PREP_BLOCKS; i += BLOCK) {
        a2 += (double)prep_partials[0 * PREP_BLOCKS + i];
        a3 += (double)prep_partials[1 * PREP_BLOCKS + i];
        a4 += (double)prep_partials[2 * PREP_BLOCKS + i];
    }
    for (int i = threadIdx.x; i < SQ_BLOCKS; i += BLOCK) {
        a5 += (double)sq_partials[i];
    }
#pragma unroll
    for (int off = 32; off > 0; off >>= 1) {
        a0 += __shfl_down(a0, off, 64);
        a1 += __shfl_down(a1, off, 64);
        a2 += __shfl_down(a2, off, 64);
        a3 += __shfl_down(a3, off, 64);
        a4 += __shfl_down(a4, off, 64);
        a5 += __shfl_down(a5, off, 64);
    }
    __shared__ double sd[6][BLOCK / 64];
    const int lane = threadIdx.x & 63, wv = threadIdx.x >> 6;
    if (lane == 0) {
        sd[0][wv] = a0; sd[1][wv] = a1; sd[2][wv] = a2;
        sd[3][wv] = a3; sd[4][wv] = a4; sd[5][wv] = a5;
    }
    __syncthreads();
    if (threadIdx.x == 0) {
        double t[6];
#pragma unroll
        for (int k = 0; k < 6; ++k) {
            double v = 0;
#pragma unroll
            for (int w = 0; w < BLOCK / 64; ++w) v += sd[k][w];
            t[k] = v;
        }
        const double logp_sum  = t[0];
        const double mask_cnt  = t[1];
        const double s1_sum    = t[2];
        const double pos_sum   = t[3];
        const double label_cnt = t[4];
        const double sq_sum    = t[5];

        const double loss      = -logp_sum / mask_cnt;
        const double semi      = SEMI_LAMBDA * s1_sum * sq_sum;
        const double edge_loss = (-pos_sum) * (EDGE_LAMBDA * EDGE_LAMBDA) / (label_cnt * label_cnt);
        out[0] = (float)(loss + semi + edge_loss);
    }
}

// ============================== FALLBACK PATH ==================================
// Original R1-proven kernels, used only if ws_size < WS_NEEDED.

__global__ __launch_bounds__(BLOCK) void edge_kernel_f(
    const float* __restrict__ poss_edge,
    const int* __restrict__ gt,
    const int* __restrict__ mask,
    const int* __restrict__ edges,
    float* __restrict__ partials)   // [4][EDGE_BLOCKS_F]
{
    const int t   = threadIdx.x & 15;
    const int grp = threadIdx.x >> 4;
    const int globalGroup = blockIdx.x * GROUPS_PER_BLOCK + grp;

    float s1 = 0.f, sq = 0.f, pos = 0.f, lcnt = 0.f;

    for (int e = globalGroup; e < E; e += TOTAL_GROUPS_F) {
        const int2 ep = *(const int2*)(edges + 2 * (size_t)e);
        const int e0 = ep.x, e1 = ep.y;

        const float* __restrict__ ra = poss_edge + (size_t)e0 * (C + 1);
        const float* __restrict__ rb = poss_edge + (size_t)e1 * (C + 1);
        const float* __restrict__ re = poss_edge + (size_t)e  * (C + 1);

        const float a0 = ra[t], a1 = ra[t + 16], a2 = ra[t + 32], a3 = ra[t + 48];
        const float b0 = rb[t], b1 = rb[t + 16], b2 = rb[t + 32], b3 = rb[t + 48];
        const float d0 = a0 - b0, d1 = a1 - b1, d2 = a2 - b2, d3 = a3 - b3;
        float acc = fmaf(d0, d0, fmaf(d1, d1, fmaf(d2, d2, d3 * d3)));
        if (t == 0) {
            const float dl = ra[C] - rb[C];
            acc = fmaf(dl, dl, acc);
        }
        sq += acc;

        const float p_last = re[C];
        const int m0 = (mask[e0] != 0);
        const int m1 = (mask[e1] != 0);
        if (m0 | m1) {
            const int g0 = gt[e0];
            const int g1 = gt[e1];
            float contrib;
            if (m0 & m1) {
                contrib = (g0 == g1) ? logf(re[g0]) : logf(p_last);
            } else if (m0) {
                contrib = logf(p_last + re[g0]);
            } else {
                contrib = logf(p_last + re[g1]);
            }
            if (t == 0) { pos += contrib; lcnt += 1.f; }
        }
        if (t == 0) s1 += 1.f - p_last;
    }

    __shared__ float s[4][BLOCK / 64];
    s1   = waveReduceSum(s1);
    sq   = waveReduceSum(sq);
    pos  = waveReduceSum(pos);
    lcnt = waveReduceSum(lcnt);
    const int lane = threadIdx.x & 63, wv = threadIdx.x >> 6;
    if (lane == 0) { s[0][wv] = s1; s[1][wv] = sq; s[2][wv] = pos; s[3][wv] = lcnt; }
    __syncthreads();
    if (threadIdx.x == 0) {
        float a = 0.f, b = 0.f, c = 0.f, d = 0.f;
#pragma unroll
        for (int w = 0; w < BLOCK / 64; ++w) {
            a += s[0][w]; b += s[1][w]; c += s[2][w]; d += s[3][w];
        }
        partials[0 * EDGE_BLOCKS_F + blockIdx.x] = a;
        partials[1 * EDGE_BLOCKS_F + blockIdx.x] = b;
        partials[2 * EDGE_BLOCKS_F + blockIdx.x] = c;
        partials[3 * EDGE_BLOCKS_F + blockIdx.x] = d;
    }
}

__global__ __launch_bounds__(BLOCK) void finalize_kernel_f(
    const float* __restrict__ node_partials,
    const float* __restrict__ edge_partials,
    float* __restrict__ out)
{
    double a0 = 0, a1 = 0, a2 = 0, a3 = 0, a4 = 0, a5 = 0;
    for (int i = threadIdx.x; i < NODE_BLOCKS_F; i += BLOCK) {
        a0 += (double)node_partials[i];
        a1 += (double)node_partials[NODE_BLOCKS_F + i];
    }
    for (int i = threadIdx.x; i < EDGE_BLOCKS_F; i += BLOCK) {
        a2 += (double)edge_partials[0 * EDGE_BLOCKS_F + i];
        a3 += (double)edge_partials[1 * EDGE_BLOCKS_F + i];
        a4 += (double)edge_partials[2 * EDGE_BLOCKS_F + i];
        a5 += (double)edge_partials[3 * EDGE_BLOCKS_F + i];
    }
#pragma unroll
    for (int off = 32; off > 0; off >>= 1) {
        a0 += __shfl_down(a0, off, 64);
        a1 += __shfl_down(a1, off, 64);
        a2 += __shfl_down(a2, off, 64);
        a3 += __shfl_down(a3, off, 64);
        a4 += __shfl_down(a4, off, 64);
        a5 += __shfl_down(a5, off, 64);
    }
    __shared__ double sd[6][BLOCK / 64];
    const int lane = threadIdx.x & 63, wv = threadIdx.x >> 6;
    if (lane == 0) {
        sd[0][wv] = a0; sd[1][wv] = a1; sd[2][wv] = a2;
        sd[3][wv] = a3; sd[4][wv] = a4; sd[5][wv] = a5;
    }
    __syncthreads();
    if (threadIdx.x == 0) {
        double t[6];
#pragma unroll
        for (int k = 0; k < 6; ++k) {
            double v = 0;
#pragma unroll
            for (int w = 0; w < BLOCK / 64; ++w) v += sd[k][w];
            t[k] = v;
        }
        const double loss      = -t[0] / t[1];
        const double semi      = SEMI_LAMBDA * t[2] * t[3];
        const double edge_loss = (-t[4]) * (EDGE_LAMBDA * EDGE_LAMBDA) / (t[5] * t[5]);
        out[0] = (float)(loss + semi + edge_loss);
    }
}

// ================================= LAUNCH ======================================

extern "C" void kernel_launch(void* const* d_in, const int* in_sizes, int n_in,
                              void* d_out, int out_size, void* d_ws, size_t ws_size,
                              hipStream_t stream) {
    const float* poss_node = (const float*)d_in[0];
    const float* poss_edge = (const float*)d_in[1];
    const int*   gt        = (const int*)d_in[2];
    const int*   mask      = (const int*)d_in[3];
    const int*   edges     = (const int*)d_in[4];
    float*       out       = (float*)d_out;

    if (ws_size >= WS_NEEDED) {
        // fast path: stream/gather separation + f16 re-layout
        unsigned short* pe16          = (unsigned short*)d_ws;
        float*          plast         = (float*)(pe16 + PE16_ELEMS);
        float*          node_partials = plast + E;                        // 2 * NODE_BLOCKS
        float*          prep_partials = node_partials + 2 * NODE_BLOCKS;  // 3 * PREP_BLOCKS
        float*          sq_partials   = prep_partials + 3 * PREP_BLOCKS;  // SQ_BLOCKS

        node_kernel<<<NODE_BLOCKS, BLOCK, 0, stream>>>(poss_node, gt, mask, node_partials);
        prep_kernel<<<PREP_BLOCKS, BLOCK, 0, stream>>>(
            poss_edge, gt, mask, edges, pe16, plast, prep_partials);
        sq_kernel<<<SQ_BLOCKS, BLOCK, 0, stream>>>(pe16, plast, edges, sq_partials);
        finalize16_kernel<<<1, BLOCK, 0, stream>>>(
            node_partials, prep_partials, sq_partials, out);
    } else {
        // fallback: original proven path (ws layout 40960 B)
        float* node_partials = (float*)d_ws;                         // 2 * NODE_BLOCKS_F
        float* edge_partials = node_partials + 2 * NODE_BLOCKS_F;    // 4 * EDGE_BLOCKS_F

        node_kernel<<<NODE_BLOCKS_F, BLOCK, 0, stream>>>(poss_node, gt, mask, node_partials);
        edge_kernel_f<<<EDGE_BLOCKS_F, BLOCK, 0, stream>>>(poss_edge, gt, mask, edges, edge_partials);
        finalize_kernel_f<<<1, BLOCK, 0, stream>>>(node_partials, edge_partials, out);
    }
}